// Round 1
// baseline (35349.979 us; speedup 1.0000x reference)
//
#include <hip/hip_runtime.h>
#include <math.h>

#define VIS 1024
#define HID 1024
#define NROW 8192
#define KDIM 2048
#define NDIM 2048
#define NSTEPS 2010
#define KLS 10
#define NWG 64
#define COLS 16   // columns per gibbs WG

// ---- ws layout (bytes) ----
#define WT_OFF   0u                      // wT: 1024x1024 f32 (4 MB)
#define LP_OFF   4194304u                // lp_row: 8192 f32
#define FE_OFF   (LP_OFF + 32768u)       // fe_row: 8192 f32
#define SBH_OFF  (FE_OFF + 32768u)       // sbuf_h: 1024 f32
#define SBV_OFF  (SBH_OFF + 4096u)       // sbuf_v: 1024 f32
#define FLG_OFF  (SBV_OFF + 4096u)       // flags: NWG x 16 ints (64B stride)
#define SSV_OFF  (FLG_OFF + 4096u)       // samples sv: 10x1024 f32
#define SSH_OFF  (SSV_OFF + 40960u)      // samples sh: 10x1024 f32
#define FES_OFF  (SSH_OFF + 40960u)      // fe_samples sum: 1 double
#define ZERO_BYTES (FES_OFF + 8u - LP_OFF)

__global__ __launch_bounds__(256) void init_zero(float* p, int n) {
    int i = blockIdx.x * 256 + threadIdx.x;
    if (i < n) p[i] = 0.f;
}

__global__ __launch_bounds__(256) void transpose_w_k(const float* __restrict__ w,
                                                     float* __restrict__ wT) {
    __shared__ float tile[32][33];
    int bx = blockIdx.x * 32, by = blockIdx.y * 32;
    int tx = threadIdx.x & 31, ty = threadIdx.x >> 5;  // ty 0..7
    #pragma unroll
    for (int m = 0; m < 4; ++m) {
        int y = by + ty + m * 8;
        tile[ty + m * 8][tx] = w[(size_t)y * 1024 + bx + tx];
    }
    __syncthreads();
    #pragma unroll
    for (int m = 0; m < 4; ++m) {
        int y = bx + ty + m * 8;
        wT[(size_t)y * 1024 + by + tx] = tile[tx][ty + m * 8];
    }
}

// ---------- GEMM1: logits = vecs@lw + lb ; fused zeta + log-posterior ----------
#define BM 128
#define BN 128
#define BK 8

__global__ __launch_bounds__(256) void gemm1_zeta_lp(
    const float* __restrict__ A, const float* __restrict__ B,
    const float* __restrict__ lb, const float* __restrict__ eps,
    const float* __restrict__ bv, const float* __restrict__ bh,
    float* __restrict__ zv, float* __restrict__ zh, float* __restrict__ lp_row)
{
    __shared__ float As[BK][BM];
    __shared__ float Bs[BK][BN];
    __shared__ float red[BM * 16];
    const int tid = threadIdx.x;
    const int n0 = blockIdx.x * BN;
    const int m0 = blockIdx.y * BM;
    const int tx = tid & 15, ty = tid >> 4;
    const int ar = tid >> 1, ac = (tid & 1) * 4;
    const int br = tid >> 5, bc = (tid & 31) * 4;

    float acc[8][8];
    #pragma unroll
    for (int i = 0; i < 8; ++i)
        #pragma unroll
        for (int j = 0; j < 8; ++j) acc[i][j] = 0.f;

    for (int k0 = 0; k0 < KDIM; k0 += BK) {
        float4 a = *reinterpret_cast<const float4*>(&A[(size_t)(m0 + ar) * KDIM + k0 + ac]);
        float4 b = *reinterpret_cast<const float4*>(&B[(size_t)(k0 + br) * NDIM + n0 + bc]);
        __syncthreads();
        As[ac + 0][ar] = a.x; As[ac + 1][ar] = a.y; As[ac + 2][ar] = a.z; As[ac + 3][ar] = a.w;
        *reinterpret_cast<float4*>(&Bs[br][bc]) = b;
        __syncthreads();
        #pragma unroll
        for (int k = 0; k < BK; ++k) {
            float av[8], bw[8];
            const float4* ap = reinterpret_cast<const float4*>(&As[k][ty * 8]);
            const float4* bp = reinterpret_cast<const float4*>(&Bs[k][tx * 8]);
            float4 a0 = ap[0], a1 = ap[1], b0 = bp[0], b1 = bp[1];
            av[0]=a0.x; av[1]=a0.y; av[2]=a0.z; av[3]=a0.w; av[4]=a1.x; av[5]=a1.y; av[6]=a1.z; av[7]=a1.w;
            bw[0]=b0.x; bw[1]=b0.y; bw[2]=b0.z; bw[3]=b0.w; bw[4]=b1.x; bw[5]=b1.y; bw[6]=b1.z; bw[7]=b1.w;
            #pragma unroll
            for (int i = 0; i < 8; ++i)
                #pragma unroll
                for (int j = 0; j < 8; ++j)
                    acc[i][j] = fmaf(av[i], bw[j], acc[i][j]);
        }
    }

    const bool isv = (n0 < VIS);
    float lpacc[8];
    #pragma unroll
    for (int i = 0; i < 8; ++i) {
        const int row = m0 + ty * 8 + i;
        float s = 0.f;
        #pragma unroll
        for (int j = 0; j < 8; ++j) {
            const int n = n0 + tx * 8 + j;
            float l = acc[i][j] + lb[n];
            float e = eps[(size_t)row * NDIM + n];
            float z = 1.f / (1.f + expf(-(l + e) * 5.f));
            float p = 1.f / (1.f + expf(-l));
            float bb;
            if (isv) { zv[(size_t)row * VIS + n] = z; bb = bv[n]; }
            else     { zh[(size_t)row * HID + (n - VIS)] = z; bb = bh[n - VIS]; }
            s += logf(z * p + (1.f - z) * (1.f - p)) + z * bb;
        }
        lpacc[i] = s;
    }
    __syncthreads();
    #pragma unroll
    for (int i = 0; i < 8; ++i) red[(ty * 8 + i) * 16 + tx] = lpacc[i];
    __syncthreads();
    if (tid < BM) {
        float s = 0.f;
        #pragma unroll
        for (int x = 0; x < 16; ++x) s += red[tid * 16 + x];
        atomicAdd(&lp_row[m0 + tid], s);
    }
}

// ---------- GEMM2: fe quadratic term: rowsum((zeta_v @ w) * zeta_h) ----------
__global__ __launch_bounds__(256) void gemm2_fe(
    const float* __restrict__ A, const float* __restrict__ B,
    const float* __restrict__ ZH, float* __restrict__ fe_row)
{
    __shared__ float As[BK][BM];
    __shared__ float Bs[BK][BN];
    __shared__ float red[BM * 16];
    const int tid = threadIdx.x;
    const int n0 = blockIdx.x * BN;
    const int m0 = blockIdx.y * BM;
    const int tx = tid & 15, ty = tid >> 4;
    const int ar = tid >> 1, ac = (tid & 1) * 4;
    const int br = tid >> 5, bc = (tid & 31) * 4;

    float acc[8][8];
    #pragma unroll
    for (int i = 0; i < 8; ++i)
        #pragma unroll
        for (int j = 0; j < 8; ++j) acc[i][j] = 0.f;

    for (int k0 = 0; k0 < 1024; k0 += BK) {
        float4 a = *reinterpret_cast<const float4*>(&A[(size_t)(m0 + ar) * 1024 + k0 + ac]);
        float4 b = *reinterpret_cast<const float4*>(&B[(size_t)(k0 + br) * 1024 + n0 + bc]);
        __syncthreads();
        As[ac + 0][ar] = a.x; As[ac + 1][ar] = a.y; As[ac + 2][ar] = a.z; As[ac + 3][ar] = a.w;
        *reinterpret_cast<float4*>(&Bs[br][bc]) = b;
        __syncthreads();
        #pragma unroll
        for (int k = 0; k < BK; ++k) {
            float av[8], bw[8];
            const float4* ap = reinterpret_cast<const float4*>(&As[k][ty * 8]);
            const float4* bp = reinterpret_cast<const float4*>(&Bs[k][tx * 8]);
            float4 a0 = ap[0], a1 = ap[1], b0 = bp[0], b1 = bp[1];
            av[0]=a0.x; av[1]=a0.y; av[2]=a0.z; av[3]=a0.w; av[4]=a1.x; av[5]=a1.y; av[6]=a1.z; av[7]=a1.w;
            bw[0]=b0.x; bw[1]=b0.y; bw[2]=b0.z; bw[3]=b0.w; bw[4]=b1.x; bw[5]=b1.y; bw[6]=b1.z; bw[7]=b1.w;
            #pragma unroll
            for (int i = 0; i < 8; ++i)
                #pragma unroll
                for (int j = 0; j < 8; ++j)
                    acc[i][j] = fmaf(av[i], bw[j], acc[i][j]);
        }
    }

    float feacc[8];
    #pragma unroll
    for (int i = 0; i < 8; ++i) {
        const int row = m0 + ty * 8 + i;
        float s = 0.f;
        #pragma unroll
        for (int j = 0; j < 8; ++j) {
            const int n = n0 + tx * 8 + j;
            s += acc[i][j] * ZH[(size_t)row * HID + n];
        }
        feacc[i] = s;
    }
    __syncthreads();
    #pragma unroll
    for (int i = 0; i < 8; ++i) red[(ty * 8 + i) * 16 + tx] = feacc[i];
    __syncthreads();
    if (tid < BM) {
        float s = 0.f;
        #pragma unroll
        for (int x = 0; x < 16; ++x) s += red[tid * 16 + x];
        atomicAdd(&fe_row[m0 + tid], s);
    }
}

// ---------- Gibbs chain: 64 persistent WGs, flag-synced, f64 decisions ----------
__device__ __forceinline__ void wait_all(int* flags, int target, int tid) {
    if (tid < NWG) {
        while (__hip_atomic_load(&flags[tid * 16], __ATOMIC_ACQUIRE,
                                 __HIP_MEMORY_SCOPE_AGENT) < target) { }
    }
    __syncthreads();
}

__global__ __launch_bounds__(256) void gibbs_k(
    const float* __restrict__ w, const float* __restrict__ wT,
    const float* __restrict__ bv, const float* __restrict__ bh,
    const float* __restrict__ u_init, const float* __restrict__ u_h,
    const float* __restrict__ u_v,
    float* __restrict__ sbh, float* __restrict__ sbv, int* __restrict__ flags,
    float* __restrict__ ssv, float* __restrict__ ssh)
{
    __shared__ float sloc[1024];
    __shared__ double red[16][COLS];
    const int tid = threadIdx.x;
    const int k = blockIdx.x;
    const int c = tid & (COLS - 1);
    const int r = tid >> 4;              // 0..15
    const int col = k * COLS + c;

    for (int m = tid; m < 1024; m += 256) sloc[m] = (u_init[m] >= 0.5f) ? 1.f : 0.f;
    __syncthreads();

    for (int t = 0; t < NSTEPS; ++t) {
        // ---- phase a: sh = bern(uh, sigmoid(bh + sv@w)) ----
        if (t > 0) {
            wait_all(flags, 2 * t, tid);
            for (int m = tid; m < 1024; m += 256) sloc[m] = sbv[m];
            __syncthreads();
        }
        double y0 = 0.0, y1 = 0.0;
        #pragma unroll 8
        for (int i = r; i < 1024; i += 32) {
            y0 += (double)(sloc[i]      * w[(size_t)i * 1024 + col]);
            y1 += (double)(sloc[i + 16] * w[(size_t)(i + 16) * 1024 + col]);
        }
        red[r][c] = y0 + y1;
        __syncthreads();
        if (r == 0) {
            double yy = red[0][c];
            #pragma unroll
            for (int q = 1; q < 16; ++q) yy += red[q][c];
            yy += (double)bh[col];
            double p = 1.0 / (1.0 + exp(-yy));
            float sres = ((double)u_h[(size_t)t * 1024 + col] >= p) ? 1.f : 0.f;
            sbh[col] = sres;
            if (t >= NSTEPS - KLS) ssh[(size_t)(t - (NSTEPS - KLS)) * 1024 + col] = sres;
        }
        __threadfence();
        __syncthreads();
        if (tid == 0)
            __hip_atomic_store(&flags[k * 16], 2 * t + 1, __ATOMIC_RELEASE,
                               __HIP_MEMORY_SCOPE_AGENT);

        // ---- phase b: sv2 = bern(uv, sigmoid(bv + sh@w^T)) ----
        wait_all(flags, 2 * t + 1, tid);
        for (int m = tid; m < 1024; m += 256) sloc[m] = sbh[m];
        __syncthreads();
        y0 = 0.0; y1 = 0.0;
        #pragma unroll 8
        for (int j = r; j < 1024; j += 32) {
            y0 += (double)(sloc[j]      * wT[(size_t)j * 1024 + col]);
            y1 += (double)(sloc[j + 16] * wT[(size_t)(j + 16) * 1024 + col]);
        }
        red[r][c] = y0 + y1;
        __syncthreads();
        if (r == 0) {
            double yy = red[0][c];
            #pragma unroll
            for (int q = 1; q < 16; ++q) yy += red[q][c];
            yy += (double)bv[col];
            double p = 1.0 / (1.0 + exp(-yy));
            float sres = ((double)u_v[(size_t)t * 1024 + col] >= p) ? 1.f : 0.f;
            sbv[col] = sres;
            if (t >= NSTEPS - KLS) ssv[(size_t)(t - (NSTEPS - KLS)) * 1024 + col] = sres;
        }
        __threadfence();
        __syncthreads();
        if (tid == 0)
            __hip_atomic_store(&flags[k * 16], 2 * t + 2, __ATOMIC_RELEASE,
                               __HIP_MEMORY_SCOPE_AGENT);
    }
}

// ---------- free energy of the 10 samples (f64) ----------
__global__ __launch_bounds__(256) void fe_samples_k(
    const float* __restrict__ w, const float* __restrict__ bv,
    const float* __restrict__ bh, const float* __restrict__ ssv,
    const float* __restrict__ ssh, double* __restrict__ fe_sum)
{
    __shared__ float svl[1024], shl[1024];
    __shared__ double dred[256];
    const int s = blockIdx.x, tid = threadIdx.x;
    for (int m = tid; m < 1024; m += 256) {
        svl[m] = ssv[(size_t)s * 1024 + m];
        shl[m] = ssh[(size_t)s * 1024 + m];
    }
    __syncthreads();
    double acc = 0.0;
    for (int jj = 0; jj < 4; ++jj) {
        int j = tid + jj * 256;
        acc += (double)(svl[j] * bv[j]) + (double)(shl[j] * bh[j]);
        if (shl[j] != 0.f) {
            double y = 0.0;
            for (int i = 0; i < 1024; ++i)
                if (svl[i] != 0.f) y += (double)w[(size_t)i * 1024 + j];
            acc += y;
        }
    }
    dred[tid] = acc;
    __syncthreads();
    for (int off = 128; off > 0; off >>= 1) {
        if (tid < off) dred[tid] += dred[tid + off];
        __syncthreads();
    }
    if (tid == 0) atomicAdd(fe_sum, dred[0]);
}

__global__ __launch_bounds__(256) void final_kl(
    const float* __restrict__ lp_row, const float* __restrict__ fe_row,
    const double* __restrict__ fe_sum, float* __restrict__ out_kl)
{
    __shared__ double dred[256];
    const int tid = threadIdx.x;
    double acc = 0.0;
    for (int r = tid; r < NROW; r += 256)
        acc += (double)lp_row[r] + (double)fe_row[r];
    dred[tid] = acc;
    __syncthreads();
    for (int off = 128; off > 0; off >>= 1) {
        if (tid < off) dred[tid] += dred[tid + off];
        __syncthreads();
    }
    if (tid == 0) out_kl[0] = (float)(dred[0] / 8192.0 - fe_sum[0] / 10.0);
}

extern "C" void kernel_launch(void* const* d_in, const int* in_sizes, int n_in,
                              void* d_out, int out_size, void* d_ws, size_t ws_size,
                              hipStream_t stream)
{
    const float* vecs   = (const float*)d_in[0];
    const float* lw     = (const float*)d_in[1];
    const float* lb     = (const float*)d_in[2];
    const float* w      = (const float*)d_in[3];
    const float* bv     = (const float*)d_in[4];
    const float* bh     = (const float*)d_in[5];
    const float* eps    = (const float*)d_in[6];
    const float* u_init = (const float*)d_in[7];
    const float* u_h    = (const float*)d_in[8];
    const float* u_v    = (const float*)d_in[9];

    float* out    = (float*)d_out;
    float* zv     = out;
    float* zh     = out + (size_t)NROW * VIS;
    float* out_kl = out + (size_t)NROW * 2048;

    char* ws = (char*)d_ws;
    float*  wT     = (float*)(ws + WT_OFF);
    float*  lp_row = (float*)(ws + LP_OFF);
    float*  fe_row = (float*)(ws + FE_OFF);
    float*  sbh    = (float*)(ws + SBH_OFF);
    float*  sbv    = (float*)(ws + SBV_OFF);
    int*    flags  = (int*)(ws + FLG_OFF);
    float*  ssv    = (float*)(ws + SSV_OFF);
    float*  ssh    = (float*)(ws + SSH_OFF);
    double* fes    = (double*)(ws + FES_OFF);

    const int zwords = (int)(ZERO_BYTES / 4);
    init_zero<<<(zwords + 255) / 256, 256, 0, stream>>>(lp_row, zwords);
    transpose_w_k<<<dim3(32, 32), 256, 0, stream>>>(w, wT);
    gemm1_zeta_lp<<<dim3(16, 64), 256, 0, stream>>>(vecs, lw, lb, eps, bv, bh, zv, zh, lp_row);
    gemm2_fe<<<dim3(8, 64), 256, 0, stream>>>(zv, w, zh, fe_row);
    gibbs_k<<<NWG, 256, 0, stream>>>(w, wT, bv, bh, u_init, u_h, u_v,
                                     sbh, sbv, flags, ssv, ssh);
    fe_samples_k<<<KLS, 256, 0, stream>>>(w, bv, bh, ssv, ssh, fes);
    final_kl<<<1, 256, 0, stream>>>(lp_row, fe_row, fes, out_kl);
}